// Round 10
// baseline (296.845 us; speedup 1.0000x reference)
//
#include <hip/hip_runtime.h>
#include <hip/hip_bf16.h>
#include <cstdint>

#define HID 1024
#define PAL 3
#define SEQ 256
#define BAT 256
#define BNEPS 1e-5f

#define NB_ENC 32768
#define NB_CW  2688
#define NB_EW8 512
#define NB_WIH 3072

typedef __attribute__((ext_vector_type(8))) short short8;
typedef __attribute__((ext_vector_type(2))) float floatx2;
typedef __attribute__((ext_vector_type(4))) float floatx4;
typedef __attribute__((ext_vector_type(8))) int int8v;

__device__ __forceinline__ ushort f2b(float f) {
  union { float f; uint32_t u; } v; v.f = f;
  uint32_t r = (v.u + 0x7FFFu + ((v.u >> 16) & 1u)) >> 16;
  return (ushort)r;
}
__device__ __forceinline__ float b2f(ushort u) {
  union { uint32_t u; float f; } v; v.u = ((uint32_t)u) << 16; return v.f;
}
__device__ __forceinline__ void gl_lds16(const ushort* g, ushort* l) {
  __builtin_amdgcn_global_load_lds(
      (const __attribute__((address_space(1))) void*)g,
      (__attribute__((address_space(3))) void*)l, 16, 0, 0);
}
__device__ __forceinline__ void gl_lds16b(const unsigned char* g, unsigned char* l) {
  __builtin_amdgcn_global_load_lds(
      (const __attribute__((address_space(1))) void*)g,
      (__attribute__((address_space(3))) void*)l, 16, 0, 0);
}

// ============ fp8 MX energy GEMM (128^2, 2-phase, T2 swizzle, K=128/MFMA) ============
// 2D grid (512 row-tiles, 8 col-tiles) — r7-measured configuration.
__global__ __launch_bounds__(256, 2)
void gemm_fp8_energy(const unsigned char* __restrict__ A, const unsigned char* __restrict__ Bt,
                     const float* __restrict__ e_b, const float* __restrict__ hws, int ldh,
                     const float* __restrict__ enw, float* __restrict__ epart, int M)
{
  __shared__ unsigned char As[128 * 128];
  __shared__ unsigned char Bs[128 * 128];
  __shared__ float ep[2][128];

  const int tid = threadIdx.x;
  const int lane = tid & 63;
  const int wave = tid >> 6;
  const int l15 = lane & 15;
  const int s = lane >> 4;
  const int wr = (wave >> 1) * 64;
  const int wc = (wave & 1) * 64;
  const int row0 = blockIdx.x * 128;
  const int col0 = blockIdx.y * 128;

  floatx4 acc[4][4] = {};

  for (int kt = 0; kt < 1024; kt += 128) {
#pragma unroll
    for (int i = 0; i < 4; ++i) {
      int chunk = i * 256 + tid;
      int r = chunk >> 3, c8 = chunk & 7;
      int sc = (c8 ^ (r & 7)) << 4;
      gl_lds16b(A + (size_t)(row0 + r) * 1024 + kt + sc,
                As + (size_t)(i * 256 + wave * 64) * 16);
      gl_lds16b(Bt + (size_t)(col0 + r) * 1024 + kt + sc,
                Bs + (size_t)(i * 256 + wave * 64) * 16);
    }
    __syncthreads();
    int8v af[4], bf[4];
#pragma unroll
    for (int mi = 0; mi < 4; ++mi) {
      int row = wr + mi * 16 + l15;
      int4 lo = *reinterpret_cast<const int4*>(&As[row * 128 + (((2 * s) ^ (row & 7)) << 4)]);
      int4 hi = *reinterpret_cast<const int4*>(&As[row * 128 + (((2 * s + 1) ^ (row & 7)) << 4)]);
      int8v v; v[0] = lo.x; v[1] = lo.y; v[2] = lo.z; v[3] = lo.w;
      v[4] = hi.x; v[5] = hi.y; v[6] = hi.z; v[7] = hi.w;
      af[mi] = v;
    }
#pragma unroll
    for (int ni = 0; ni < 4; ++ni) {
      int row = wc + ni * 16 + l15;
      int4 lo = *reinterpret_cast<const int4*>(&Bs[row * 128 + (((2 * s) ^ (row & 7)) << 4)]);
      int4 hi = *reinterpret_cast<const int4*>(&Bs[row * 128 + (((2 * s + 1) ^ (row & 7)) << 4)]);
      int8v v; v[0] = lo.x; v[1] = lo.y; v[2] = lo.z; v[3] = lo.w;
      v[4] = hi.x; v[5] = hi.y; v[6] = hi.z; v[7] = hi.w;
      bf[ni] = v;
    }
#pragma unroll
    for (int mi = 0; mi < 4; ++mi)
#pragma unroll
      for (int ni = 0; ni < 4; ++ni)
        acc[mi][ni] = __builtin_amdgcn_mfma_scale_f32_16x16x128_f8f6f4(
            af[mi], bf[ni], acc[mi][ni], 0, 0, 0, 0x7F7F7F7F, 0, 0x7F7F7F7F);
    __syncthreads();
  }

  float rs[4][4];
#pragma unroll
  for (int mi = 0; mi < 4; ++mi) {
#pragma unroll
    for (int q = 0; q < 4; ++q) {
      int m = row0 + wr + mi * 16 + (lane >> 4) * 4 + q;
      int b = m & (BAT - 1);
      float v = 0.f;
#pragma unroll
      for (int ni = 0; ni < 4; ++ni) {
        int cg = col0 + wc + ni * 16 + l15;
        float e = acc[mi][ni][q] * 0.015625f + e_b[cg] + hws[(size_t)b * ldh + cg];
        v += enw[cg] * (1.f / (1.f + __expf(-e)));
      }
#pragma unroll
      for (int o = 1; o < 16; o <<= 1) v += __shfl_xor(v, o);
      rs[mi][q] = v;
    }
  }
  if (l15 == 0) {
#pragma unroll
    for (int mi = 0; mi < 4; ++mi)
#pragma unroll
      for (int q = 0; q < 4; ++q)
        ep[wave & 1][wr + mi * 16 + (lane >> 4) * 4 + q] = rs[mi][q];
  }
  __syncthreads();
  if (tid < 128)
    epart[(size_t)blockIdx.y * M + row0 + tid] = ep[0][tid] + ep[1][tid];
}

// ---------------- bf16 GEMM, m97 structure + T2 swizzle ----------------
template<int EPI>
__global__ __launch_bounds__(256, 2)
void gemm_bf(const ushort* __restrict__ A, int lda,
             const ushort* __restrict__ Bt, int ldb,
             const float* __restrict__ bias,
             float* __restrict__ C, int ldc,
             int M, int K,
             const float* __restrict__ hws, int ldh,
             const float* __restrict__ enw,
             float* __restrict__ epart)
{
  __shared__ ushort As[128 * 64];
  __shared__ ushort Bs[128 * 64];
  __shared__ float ep[2][128];

  const int tid = threadIdx.x;
  const int lane = tid & 63;
  const int wave = tid >> 6;
  const int l15 = lane & 15;
  const int wr = (wave >> 1) * 64;
  const int wc = (wave & 1) * 64;
  const int row0 = blockIdx.x * 128;
  const int col0 = blockIdx.y * 128;

  floatx4 acc[4][4] = {};

  for (int kt = 0; kt < K; kt += 64) {
#pragma unroll
    for (int i = 0; i < 4; ++i) {
      int chunk = i * 256 + tid;
      int r = chunk >> 3, c8 = chunk & 7;
      int sc = (c8 ^ (r & 7)) << 3;
      gl_lds16(A + (size_t)(row0 + r) * lda + kt + sc,
               (ushort*)As + (size_t)(i * 256 + wave * 64) * 8);
      gl_lds16(Bt + (size_t)(col0 + r) * ldb + kt + sc,
               (ushort*)Bs + (size_t)(i * 256 + wave * 64) * 8);
    }
    __syncthreads();
#pragma unroll
    for (int kk = 0; kk < 2; ++kk) {
      const int kc = (lane >> 4) + kk * 4;
      short8 af[4], bf[4];
#pragma unroll
      for (int mi = 0; mi < 4; ++mi) {
        int row = wr + mi * 16 + l15;
        af[mi] = *reinterpret_cast<const short8*>(&As[row * 64 + ((kc ^ (row & 7)) << 3)]);
      }
#pragma unroll
      for (int ni = 0; ni < 4; ++ni) {
        int row = wc + ni * 16 + l15;
        bf[ni] = *reinterpret_cast<const short8*>(&Bs[row * 64 + ((kc ^ (row & 7)) << 3)]);
      }
#pragma unroll
      for (int mi = 0; mi < 4; ++mi)
#pragma unroll
        for (int ni = 0; ni < 4; ++ni)
          acc[mi][ni] = __builtin_amdgcn_mfma_f32_16x16x32_bf16(af[mi], bf[ni], acc[mi][ni], 0, 0, 0);
    }
    __syncthreads();
  }

  if (EPI == 0 || EPI == 2) {
#pragma unroll
    for (int mi = 0; mi < 4; ++mi) {
      int rloc = wr + mi * 16 + (lane >> 4) * 4;
#pragma unroll
      for (int ni = 0; ni < 4; ++ni) {
        int cg = col0 + wc + ni * 16 + l15;
        float bv = bias ? bias[cg] : 0.f;
#pragma unroll
        for (int q = 0; q < 4; ++q) {
          float v = acc[mi][ni][q] + bv;
          if (EPI == 2) v = fmaxf(v, 0.f);
          C[(size_t)(row0 + rloc + q) * ldc + cg] = v;
        }
      }
    }
  } else {
    float rs[4][4];
#pragma unroll
    for (int mi = 0; mi < 4; ++mi) {
#pragma unroll
      for (int q = 0; q < 4; ++q) {
        int m = row0 + wr + mi * 16 + (lane >> 4) * 4 + q;
        int b = m & (BAT - 1);
        float v = 0.f;
#pragma unroll
        for (int ni = 0; ni < 4; ++ni) {
          int cg = col0 + wc + ni * 16 + l15;
          float e = acc[mi][ni][q] + bias[cg] + hws[(size_t)b * ldh + cg];
          v += enw[cg] * (1.f / (1.f + __expf(-e)));
        }
#pragma unroll
        for (int o = 1; o < 16; o <<= 1) v += __shfl_xor(v, o);
        rs[mi][q] = v;
      }
    }
    if (l15 == 0) {
#pragma unroll
      for (int mi = 0; mi < 4; ++mi)
#pragma unroll
        for (int q = 0; q < 4; ++q)
          ep[wave & 1][wr + mi * 16 + (lane >> 4) * 4 + q] = rs[mi][q];
    }
    __syncthreads();
    if (tid < 128)
      epart[(size_t)blockIdx.y * M + row0 + tid] = ep[0][tid] + ep[1][tid];
  }
}

// ---------------- fp32-input GEMM (deep fallback only) ----------------
template<int EPI, bool GUARDB>
__global__ __launch_bounds__(256, 2)
void gemm_bt(const float* __restrict__ A, int lda,
             const float* __restrict__ Bt, int ldb, int Kb,
             const float* __restrict__ bias,
             float* __restrict__ C, int ldc,
             int M, int K,
             const float* __restrict__ hws,
             const float* __restrict__ enw,
             float* __restrict__ epart)
{
  __shared__ ushort As[128 * 72];
  __shared__ ushort Bs[128 * 72];
  __shared__ float ep[2][128];

  const int tid = threadIdx.x;
  const int lane = tid & 63;
  const int wave = tid >> 6;
  const int wr = (wave >> 1) * 64;
  const int wc = (wave & 1) * 64;
  const int row0 = blockIdx.x * 128;
  const int col0 = blockIdx.y * 128;
  const int rb = tid >> 4;
  const int c4 = tid & 15;

  floatx4 acc[4][4] = {};

  for (int kt = 0; kt < K; kt += 64) {
    float4 aL[8], bL[8];
#pragma unroll
    for (int it = 0; it < 8; ++it) {
      int r = it * 16 + rb;
      aL[it] = *reinterpret_cast<const float4*>(A + (size_t)(row0 + r) * lda + kt + c4 * 4);
      if (GUARDB) {
        int k0 = kt + c4 * 4;
        const float* bp = Bt + (size_t)(col0 + r) * ldb;
        bL[it].x = (k0 + 0 < Kb) ? bp[k0 + 0] : 0.f;
        bL[it].y = (k0 + 1 < Kb) ? bp[k0 + 1] : 0.f;
        bL[it].z = (k0 + 2 < Kb) ? bp[k0 + 2] : 0.f;
        bL[it].w = (k0 + 3 < Kb) ? bp[k0 + 3] : 0.f;
      } else {
        bL[it] = *reinterpret_cast<const float4*>(Bt + (size_t)(col0 + r) * ldb + kt + c4 * 4);
      }
    }
    __syncthreads();
#pragma unroll
    for (int it = 0; it < 8; ++it) {
      int r = it * 16 + rb;
      ushort4 av = make_ushort4(f2b(aL[it].x), f2b(aL[it].y), f2b(aL[it].z), f2b(aL[it].w));
      ushort4 bv = make_ushort4(f2b(bL[it].x), f2b(bL[it].y), f2b(bL[it].z), f2b(bL[it].w));
      *reinterpret_cast<ushort4*>(&As[r * 72 + c4 * 4]) = av;
      *reinterpret_cast<ushort4*>(&Bs[r * 72 + c4 * 4]) = bv;
    }
    __syncthreads();
#pragma unroll
    for (int kk = 0; kk < 2; ++kk) {
      const int ko = (lane >> 4) * 8 + kk * 32;
      short8 af[4], bf[4];
#pragma unroll
      for (int mi = 0; mi < 4; ++mi)
        af[mi] = *reinterpret_cast<const short8*>(&As[(wr + mi * 16 + (lane & 15)) * 72 + ko]);
#pragma unroll
      for (int ni = 0; ni < 4; ++ni)
        bf[ni] = *reinterpret_cast<const short8*>(&Bs[(wc + ni * 16 + (lane & 15)) * 72 + ko]);
#pragma unroll
      for (int mi = 0; mi < 4; ++mi)
#pragma unroll
        for (int ni = 0; ni < 4; ++ni)
          acc[mi][ni] = __builtin_amdgcn_mfma_f32_16x16x32_bf16(af[mi], bf[ni], acc[mi][ni], 0, 0, 0);
    }
  }

  if (EPI == 0 || EPI == 2) {
#pragma unroll
    for (int mi = 0; mi < 4; ++mi) {
      int rloc = wr + mi * 16 + (lane >> 4) * 4;
#pragma unroll
      for (int ni = 0; ni < 4; ++ni) {
        int cg = col0 + wc + ni * 16 + (lane & 15);
        float bv = bias ? bias[cg] : 0.f;
#pragma unroll
        for (int q = 0; q < 4; ++q) {
          float v = acc[mi][ni][q] + bv;
          if (EPI == 2) v = fmaxf(v, 0.f);
          C[(size_t)(row0 + rloc + q) * ldc + cg] = v;
        }
      }
    }
  } else {
    float rs[4][4];
#pragma unroll
    for (int mi = 0; mi < 4; ++mi) {
#pragma unroll
      for (int q = 0; q < 4; ++q) {
        int m = row0 + wr + mi * 16 + (lane >> 4) * 4 + q;
        int b = m & (BAT - 1);
        float v = 0.f;
#pragma unroll
        for (int ni = 0; ni < 4; ++ni) {
          int cg = col0 + wc + ni * 16 + (lane & 15);
          float e = acc[mi][ni][q] + bias[cg] + hws[(size_t)b * HID + cg];
          float sg = 1.f / (1.f + __expf(-e));
          v += sg * enw[cg];
        }
#pragma unroll
        for (int o = 1; o < 16; o <<= 1) v += __shfl_xor(v, o);
        rs[mi][q] = v;
      }
    }
    if ((lane & 15) == 0) {
#pragma unroll
      for (int mi = 0; mi < 4; ++mi)
#pragma unroll
        for (int q = 0; q < 4; ++q)
          ep[wave & 1][wr + mi * 16 + (lane >> 4) * 4 + q] = rs[mi][q];
    }
    __syncthreads();
    if (tid < 128)
      epart[(size_t)blockIdx.y * M + row0 + tid] = ep[0][tid] + ep[1][tid];
  }
}

// ---------------- fused prep megakernel (tier 1; no dead ew_bf conversion) ----------
__global__ __launch_bounds__(256)
void megaprep(const float* __restrict__ enc,
              const float* __restrict__ hw, const float* __restrict__ whh,
              const float* __restrict__ ew, const float* __restrict__ o1w,
              const float* __restrict__ ldh, const float* __restrict__ wih,
              const float* __restrict__ pal,
              const float* __restrict__ h_b, const float* __restrict__ b_hh,
              unsigned char* __restrict__ enc8,
              ushort* __restrict__ whgh,
              ushort* __restrict__ o1b, ushort* __restrict__ ldhb,
              unsigned char* __restrict__ ew8, ushort* __restrict__ wihb,
              ushort* __restrict__ ginb, float* __restrict__ bias_cat)
{
  const int blk = blockIdx.x;
  const int tid = threadIdx.x;
  if (blk < NB_ENC) {
    size_t i = (size_t)blk * 2048 + (size_t)tid * 8;
    float4 a = *reinterpret_cast<const float4*>(enc + i);
    float4 b = *reinterpret_cast<const float4*>(enc + i + 4);
    int w01 = __builtin_amdgcn_cvt_pk_fp8_f32(a.x, a.y, 0, false);
    int w03 = __builtin_amdgcn_cvt_pk_fp8_f32(a.z, a.w, w01, true);
    int w45 = __builtin_amdgcn_cvt_pk_fp8_f32(b.x, b.y, 0, false);
    int w47 = __builtin_amdgcn_cvt_pk_fp8_f32(b.z, b.w, w45, true);
    int2 pk; pk.x = w03; pk.y = w47;
    *reinterpret_cast<int2*>(enc8 + i) = pk;
  } else if (blk < NB_ENC + NB_CW) {
    int cw = blk - NB_ENC;
    const float* src; ushort* dst; size_t off;
    if (cw < 512)        { src = hw;  dst = whgh;            off = (size_t)cw * 2048; }
    else if (cw < 2048)  { src = whh; dst = whgh + 1048576;  off = (size_t)(cw - 512) * 2048; }
    else if (cw < 2560)  { src = o1w; dst = o1b;             off = (size_t)(cw - 2048) * 2048; }
    else                 { src = ldh; dst = ldhb;            off = (size_t)(cw - 2560) * 2048; }
    size_t i = off + (size_t)tid * 8;
    float4 a = *reinterpret_cast<const float4*>(src + i);
    float4 b = *reinterpret_cast<const float4*>(src + i + 4);
    ushort o[8] = {f2b(a.x), f2b(a.y), f2b(a.z), f2b(a.w),
                   f2b(b.x), f2b(b.y), f2b(b.z), f2b(b.w)};
    *reinterpret_cast<short8*>(dst + i) = *reinterpret_cast<short8*>(o);
  } else if (blk < NB_ENC + NB_CW + NB_EW8) {
    size_t i = (size_t)(blk - NB_ENC - NB_CW) * 2048 + (size_t)tid * 8;
    float4 a = *reinterpret_cast<const float4*>(ew + i);
    float4 b = *reinterpret_cast<const float4*>(ew + i + 4);
    int w01 = __builtin_amdgcn_cvt_pk_fp8_f32(a.x * 64.f, a.y * 64.f, 0, false);
    int w03 = __builtin_amdgcn_cvt_pk_fp8_f32(a.z * 64.f, a.w * 64.f, w01, true);
    int w45 = __builtin_amdgcn_cvt_pk_fp8_f32(b.x * 64.f, b.y * 64.f, 0, false);
    int w47 = __builtin_amdgcn_cvt_pk_fp8_f32(b.z * 64.f, b.w * 64.f, w45, true);
    int2 pk; pk.x = w03; pk.y = w47;
    *reinterpret_cast<int2*>(ew8 + i) = pk;
  } else if (blk < NB_ENC + NB_CW + NB_EW8 + NB_WIH) {
    int r = blk - NB_ENC - NB_CW - NB_EW8;
    for (int c = tid; c < 1088; c += 256) {
      ushort v = 0;
      if (c < 1024)      v = f2b(wih[(size_t)r * 1027 + 3 + c]);
      else if (c < 1027) v = f2b(wih[(size_t)r * 1027 + (c - 1024)]);
      wihb[(size_t)r * 1088 + c] = v;
    }
  } else {
    ginb[tid * 1088 + 1024] = f2b(pal[tid * 3 + 0]);
    ginb[tid * 1088 + 1025] = f2b(pal[tid * 3 + 1]);
    ginb[tid * 1088 + 1026] = f2b(pal[tid * 3 + 2]);
    for (int k = 1027; k < 1088; ++k) ginb[tid * 1088 + k] = 0;
    for (int j = tid; j < 4096; j += 256) bias_cat[j] = (j < 1024) ? h_b[j] : b_hh[j - 1024];
  }
}

// ------- merged softmax + context, fp8 enc input (tier 1; one block per batch) -------
__global__ void softmax_context_fp8(const float* __restrict__ epart, int ntiles,
                                    const unsigned char* __restrict__ enc8,
                                    float* __restrict__ att, float* __restrict__ ctx,
                                    ushort* __restrict__ ginb) {
  int b = blockIdx.x, s = threadIdx.x;
  __shared__ float wl[256];
  __shared__ float rm[4], rsum[4];
  float e = 0.f;
  for (int nt = 0; nt < ntiles; ++nt) e += epart[(size_t)nt * (SEQ * BAT) + s * BAT + b];
  float m = e;
  for (int o = 1; o < 64; o <<= 1) m = fmaxf(m, __shfl_xor(m, o));
  if ((s & 63) == 0) rm[s >> 6] = m;
  __syncthreads();
  m = fmaxf(fmaxf(rm[0], rm[1]), fmaxf(rm[2], rm[3]));
  float ex = __expf(e - m);
  float sum = ex;
  for (int o = 1; o < 64; o <<= 1) sum += __shfl_xor(sum, o);
  if ((s & 63) == 0) rsum[s >> 6] = sum;
  __syncthreads();
  sum = rsum[0] + rsum[1] + rsum[2] + rsum[3];
  float w = ex / sum;
  att[b * SEQ + s] = w;
  wl[s] = w;
  __syncthreads();
  int h0 = s * 4;
  const unsigned char* ep = enc8 + (size_t)b * HID + h0;
  float c0 = 0.f, c1 = 0.f, c2 = 0.f, c3 = 0.f;
#pragma unroll 8
  for (int s2 = 0; s2 < SEQ; ++s2) {
    unsigned int v = *reinterpret_cast<const unsigned int*>(ep + (size_t)s2 * BAT * HID);
    floatx2 lo = __builtin_amdgcn_cvt_pk_f32_fp8(v, false);
    floatx2 hi = __builtin_amdgcn_cvt_pk_f32_fp8(v, true);
    float ww = wl[s2];
    c0 += ww * lo[0]; c1 += ww * lo[1]; c2 += ww * hi[0]; c3 += ww * hi[1];
  }
  float4 o = {c0, c1, c2, c3};
  *reinterpret_cast<float4*>(ctx + (size_t)b * HID + h0) = o;
  ushort g[4] = {f2b(c0), f2b(c1), f2b(c2), f2b(c3)};
  *reinterpret_cast<ushort4*>(ginb + (size_t)b * 1088 + h0) = *reinterpret_cast<ushort4*>(g);
}

// ---------------- merged softmax + context, bf16 enc (tier 2) ----------------
__global__ void softmax_context(const float* __restrict__ epart, int ntiles,
                                const ushort* __restrict__ encb,
                                float* __restrict__ att, float* __restrict__ ctx,
                                ushort* __restrict__ ginb) {
  int b = blockIdx.x, s = threadIdx.x;
  __shared__ float wl[256];
  __shared__ float rm[4], rsum[4];
  float e = 0.f;
  for (int nt = 0; nt < ntiles; ++nt) e += epart[(size_t)nt * (SEQ * BAT) + s * BAT + b];
  float m = e;
  for (int o = 1; o < 64; o <<= 1) m = fmaxf(m, __shfl_xor(m, o));
  if ((s & 63) == 0) rm[s >> 6] = m;
  __syncthreads();
  m = fmaxf(fmaxf(rm[0], rm[1]), fmaxf(rm[2], rm[3]));
  float ex = __expf(e - m);
  float sum = ex;
  for (int o = 1; o < 64; o <<= 1) sum += __shfl_xor(sum, o);
  if ((s & 63) == 0) rsum[s >> 6] = sum;
  __syncthreads();
  sum = rsum[0] + rsum[1] + rsum[2] + rsum[3];
  float w = ex / sum;
  att[b * SEQ + s] = w;
  wl[s] = w;
  __syncthreads();
  int h0 = s * 4;
  const ushort* ep = encb + (size_t)b * HID + h0;
  float c0 = 0.f, c1 = 0.f, c2 = 0.f, c3 = 0.f;
#pragma unroll 8
  for (int s2 = 0; s2 < SEQ; ++s2) {
    ushort4 v = *reinterpret_cast<const ushort4*>(ep + (size_t)s2 * BAT * HID);
    float ww = wl[s2];
    c0 += ww * b2f(v.x); c1 += ww * b2f(v.y); c2 += ww * b2f(v.z); c3 += ww * b2f(v.w);
  }
  float4 o = {c0, c1, c2, c3};
  *reinterpret_cast<float4*>(ctx + (size_t)b * HID + h0) = o;
  ushort g[4] = {f2b(c0), f2b(c1), f2b(c2), f2b(c3)};
  *reinterpret_cast<ushort4*>(ginb + (size_t)b * 1088 + h0) = *reinterpret_cast<ushort4*>(g);
}

// ---------------- legacy kernels (fallback tiers) ----------------
__global__ void f2b_kernel(const float* __restrict__ in, ushort* __restrict__ out, size_t n) {
  size_t i = ((size_t)blockIdx.x * 256 + threadIdx.x) * 8;
  if (i + 8 > n) return;
  float4 a = *reinterpret_cast<const float4*>(in + i);
  float4 b = *reinterpret_cast<const float4*>(in + i + 4);
  ushort o[8] = {f2b(a.x), f2b(a.y), f2b(a.z), f2b(a.w),
                 f2b(b.x), f2b(b.y), f2b(b.z), f2b(b.w)};
  *reinterpret_cast<short8*>(out + i) = *reinterpret_cast<short8*>(o);
}

__global__ void conv_weights(const float* __restrict__ hw, const float* __restrict__ whh,
                             const float* __restrict__ ew, const float* __restrict__ o1w,
                             const float* __restrict__ ldh,
                             ushort* __restrict__ whgh, ushort* __restrict__ ewb,
                             ushort* __restrict__ o1b, ushort* __restrict__ ldhb) {
  int blk = blockIdx.x;
  const float* src; ushort* dst; size_t off;
  if (blk < 512)        { src = hw;  dst = whgh;            off = (size_t)blk * 2048; }
  else if (blk < 2048)  { src = whh; dst = whgh + 1048576;  off = (size_t)(blk - 512) * 2048; }
  else if (blk < 2560)  { src = ew;  dst = ewb;             off = (size_t)(blk - 2048) * 2048; }
  else if (blk < 3072)  { src = o1w; dst = o1b;             off = (size_t)(blk - 2560) * 2048; }
  else                  { src = ldh; dst = ldhb;            off = (size_t)(blk - 3072) * 2048; }
  size_t i = off + (size_t)threadIdx.x * 8;
  float4 a = *reinterpret_cast<const float4*>(src + i);
  float4 b = *reinterpret_cast<const float4*>(src + i + 4);
  ushort o[8] = {f2b(a.x), f2b(a.y), f2b(a.z), f2b(a.w),
                 f2b(b.x), f2b(b.y), f2b(b.z), f2b(b.w)};
  *reinterpret_cast<short8*>(dst + i) = *reinterpret_cast<short8*>(o);
}

__global__ void pack_wih(const float* __restrict__ in, ushort* __restrict__ out) {
  int r = blockIdx.x;
  int c = blockIdx.y * 256 + threadIdx.x;
  if (c < 1088) {
    ushort v = 0;
    if (c < 1024)      v = f2b(in[(size_t)r * 1027 + 3 + c]);
    else if (c < 1027) v = f2b(in[(size_t)r * 1027 + (c - 1024)]);
    out[(size_t)r * 1088 + c] = v;
  }
}

__global__ void softmax_kernel(const float* __restrict__ epart, int ntiles,
                               float* __restrict__ wsm, float* __restrict__ att) {
  int b = blockIdx.x, s = threadIdx.x;
  float e = 0.f;
  for (int nt = 0; nt < ntiles; ++nt) e += epart[(size_t)nt * (SEQ * BAT) + s * BAT + b];
  float m = e;
  for (int o = 1; o < 64; o <<= 1) m = fmaxf(m, __shfl_xor(m, o));
  __shared__ float rm[4], rsum[4];
  if ((s & 63) == 0) rm[s >> 6] = m;
  __syncthreads();
  m = fmaxf(fmaxf(rm[0], rm[1]), fmaxf(rm[2], rm[3]));
  float ex = __expf(e - m);
  float sum = ex;
  for (int o = 1; o < 64; o <<= 1) sum += __shfl_xor(sum, o);
  if ((s & 63) == 0) rsum[s >> 6] = sum;
  __syncthreads();
  sum = rsum[0] + rsum[1] + rsum[2] + rsum[3];
  float w = ex / sum;
  wsm[s * BAT + b] = w;
  att[b * SEQ + s] = w;
}

__global__ void prep_small(const float* __restrict__ pal, ushort* __restrict__ ginb,
                           const float* __restrict__ h_b, const float* __restrict__ b_hh,
                           float* __restrict__ bias_cat) {
  int t = threadIdx.x;
  ginb[t * 1088 + 1024] = f2b(pal[t * 3 + 0]);
  ginb[t * 1088 + 1025] = f2b(pal[t * 3 + 1]);
  ginb[t * 1088 + 1026] = f2b(pal[t * 3 + 2]);
  for (int k = 1027; k < 1088; ++k) ginb[t * 1088 + k] = 0;
  for (int j = t; j < 4096; j += 256) bias_cat[j] = (j < 1024) ? h_b[j] : b_hh[j - 1024];
}

__global__ void prep_gin(const float* __restrict__ pal, float* __restrict__ gin) {
  int b = threadIdx.x;
  gin[b * 1088 + 0] = pal[b * 3 + 0];
  gin[b * 1088 + 1] = pal[b * 3 + 1];
  gin[b * 1088 + 2] = pal[b * 3 + 2];
  for (int k = 1027; k < 1088; ++k) gin[b * 1088 + k] = 0.f;
}

__global__ void context_kernel(const float* __restrict__ enc, const float* __restrict__ wsm,
                               float* __restrict__ ctx, float* __restrict__ gin) {
  int b = blockIdx.x, hc = blockIdx.y, t = threadIdx.x;
  __shared__ float wl[256];
  wl[t] = wsm[t * BAT + b];
  __syncthreads();
  int h = hc * 256 + t;
  const float* ep = enc + (size_t)b * HID + h;
  float c = 0.f;
#pragma unroll 8
  for (int s = 0; s < SEQ; ++s) c += wl[s] * ep[(size_t)s * BAT * HID];
  ctx[(size_t)b * HID + h] = c;
  gin[b * 1088 + 3 + h] = c;
}

__global__ void gru_combine(const float* __restrict__ gi, const float* __restrict__ gh, int ghs,
                            const float* __restrict__ hprev, float* __restrict__ hout,
                            ushort* __restrict__ hb) {
  int idx = blockIdx.x * 256 + threadIdx.x;
  int b = idx >> 10, j = idx & 1023;
  size_t gib = (size_t)b * 3 * HID;
  size_t ghb = (size_t)b * ghs;
  float ir = gi[gib + j], iz = gi[gib + HID + j], in_ = gi[gib + 2 * HID + j];
  float hr = gh[ghb + j], hz = gh[ghb + HID + j], hn = gh[ghb + 2 * HID + j];
  float r = 1.f / (1.f + __expf(-(ir + hr)));
  float z = 1.f / (1.f + __expf(-(iz + hz)));
  float n = tanhf(in_ + r * hn);
  float v = (1.f - z) * n + z * hprev[idx];
  hout[idx] = v;
  if (hb) hb[idx] = f2b(v);
}

__global__ void bn_stats(const float* __restrict__ x1, const float* __restrict__ bnw,
                         const float* __restrict__ bnb, float* __restrict__ sj,
                         float* __restrict__ tj) {
  int j = blockIdx.x * 256 + threadIdx.x;
  float s = 0.f, ss = 0.f;
  for (int b = 0; b < BAT; ++b) {
    float x = x1[(size_t)b * HID + j];
    s += x; ss += x * x;
  }
  float mu = s * (1.f / BAT);
  float var = ss * (1.f / BAT) - mu * mu;
  float rstd = rsqrtf(var + BNEPS);
  float sc = bnw[j] * rstd;
  sj[j] = sc;
  tj[j] = bnb[j] - mu * sc;
}

__global__ void palette_kernel(const float* __restrict__ x1, const float* __restrict__ sj,
                               const float* __restrict__ tj, const float* __restrict__ w2,
                               const float* __restrict__ b2, float* __restrict__ outp) {
  int b = blockIdx.x, t = threadIdx.x;
  float p0 = 0.f, p1 = 0.f, p2 = 0.f;
  for (int j = t; j < HID; j += 256) {
    float xn = x1[(size_t)b * HID + j] * sj[j] + tj[j];
    p0 += xn * w2[j];
    p1 += xn * w2[HID + j];
    p2 += xn * w2[2 * HID + j];
  }
  for (int o = 1; o < 64; o <<= 1) {
    p0 += __shfl_xor(p0, o); p1 += __shfl_xor(p1, o); p2 += __shfl_xor(p2, o);
  }
  __shared__ float r0[4], r1[4], r2[4];
  int w = t >> 6;
  if ((t & 63) == 0) { r0[w] = p0; r1[w] = p1; r2[w] = p2; }
  __syncthreads();
  if (t == 0) {
    outp[b * 3 + 0] = r0[0] + r0[1] + r0[2] + r0[3] + b2[0];
    outp[b * 3 + 1] = r1[0] + r1[1] + r1[2] + r1[3] + b2[1];
    outp[b * 3 + 2] = r2[0] + r2[1] + r2[2] + r2[3] + b2[2];
  }
}

extern "C" void kernel_launch(void* const* d_in, const int* in_sizes, int n_in,
                              void* d_out, int out_size, void* d_ws, size_t ws_size,
                              hipStream_t stream) {
  const float* pal_in = (const float*)d_in[0];
  const float* ldh    = (const float*)d_in[1];
  const float* enc    = (const float*)d_in[2];
  const float* e_w    = (const float*)d_in[3];
  const float* e_b    = (const float*)d_in[4];
  const float* h_w    = (const float*)d_in[5];
  const float* h_b    = (const float*)d_in[6];
  const float* en_w   = (const float*)d_in[7];
  const float* w_ih   = (const float*)d_in[9];
  const float* w_hh   = (const float*)d_in[10];
  const float* b_ih   = (const float*)d_in[11];
  const float* b_hh   = (const float*)d_in[12];
  const float* o1_w   = (const float*)d_in[13];
  const float* o1_b   = (const float*)d_in[14];
  const float* bnw    = (const float*)d_in[15];
  const float* bnb    = (const float*)d_in[16];
  const float* o2_w   = (const float*)d_in[17];
  const float* o2_b   = (const float*)d_in[18];

  float* out = (float*)d_out;
  float* out_pal = out;
  float* out_ctx = out + BAT * PAL;
  float* out_hid = out_ctx + BAT * HID;
  float* out_att = out_hid + BAT * HID;

  dim3 blk(256);

  char* p0 = (char*)d_ws;
  char* p = p0;
  auto carve = [&](size_t bytes) { char* r = p; p += (bytes + 255) & ~(size_t)255; return r; };
  ushort* enc_bf  = (ushort*)carve((size_t)SEQ * BAT * HID * 2);
  ushort* whgh_bf = (ushort*)carve((size_t)4 * HID * HID * 2);
  ushort* ew_bf   = (ushort*)carve((size_t)HID * HID * 2);
  ushort* wih_bf  = (ushort*)carve((size_t)3 * HID * 1088 * 2);
  ushort* o1_bf   = (ushort*)carve((size_t)HID * HID * 2);
  ushort* ldh_bf  = (ushort*)carve((size_t)BAT * HID * 2);
  ushort* gin_bf  = (ushort*)carve((size_t)BAT * 1088 * 2);
  ushort* hid_bf  = (ushort*)carve((size_t)BAT * HID * 2);
  float* hgh      = (float*)carve((size_t)BAT * 4 * HID * 4);
  float* bias_cat = (float*)carve((size_t)4 * HID * 4);
  float* epart    = (float*)carve((size_t)8 * SEQ * BAT * 4);
  float* wsm      = (float*)carve((size_t)SEQ * BAT * 4);
  float* gi       = (float*)carve((size_t)BAT * 3 * HID * 4);
  float* x1       = (float*)carve((size_t)BAT * HID * 4);
  float* sj       = (float*)carve((size_t)HID * 4);
  float* tj       = (float*)carve((size_t)HID * 4);
  size_t need_mid = (size_t)(p - p0);
  unsigned char* enc8 = (unsigned char*)carve((size_t)SEQ * BAT * HID);
  unsigned char* ew8  = (unsigned char*)carve((size_t)HID * HID);
  size_t need_full = (size_t)(p - p0);

  if (ws_size >= need_full) {
    // -------- tier 1: fp8 MX energy + fp8 context --------
    megaprep<<<dim3(NB_ENC + NB_CW + NB_EW8 + NB_WIH + 1), blk, 0, stream>>>(
        enc, h_w, w_hh, e_w, o1_w, ldh, w_ih, pal_in, h_b, b_hh,
        enc8, whgh_bf, o1_bf, ldh_bf, ew8, wih_bf, gin_bf, bias_cat);
    gemm_bf<0><<<dim3(2, 32), blk, 0, stream>>>(
        ldh_bf, HID, whgh_bf, HID, bias_cat, hgh, 4 * HID, BAT, HID,
        nullptr, 0, nullptr, nullptr);
    gemm_fp8_energy<<<dim3(512, 8), blk, 0, stream>>>(
        enc8, ew8, e_b, hgh, 4 * HID, en_w, epart, SEQ * BAT);
    softmax_context_fp8<<<dim3(256), blk, 0, stream>>>(
        epart, 8, enc8, out_att, out_ctx, gin_bf);
    gemm_bf<0><<<dim3(2, 24), blk, 0, stream>>>(
        gin_bf, 1088, wih_bf, 1088, b_ih, gi, 3 * HID, BAT, 1088,
        nullptr, 0, nullptr, nullptr);
    gru_combine<<<dim3(1024), blk, 0, stream>>>(gi, hgh + HID, 4 * HID, ldh, out_hid, hid_bf);
    gemm_bf<2><<<dim3(2, 8), blk, 0, stream>>>(
        hid_bf, HID, o1_bf, HID, o1_b, x1, HID, BAT, HID,
        nullptr, 0, nullptr, nullptr);
    bn_stats<<<dim3(4), blk, 0, stream>>>(x1, bnw, bnb, sj, tj);
    palette_kernel<<<dim3(256), blk, 0, stream>>>(x1, sj, tj, o2_w, o2_b, out_pal);
  } else if (ws_size >= need_mid) {
    // -------- tier 2: bf16 path --------
    conv_weights<<<dim3(3200), blk, 0, stream>>>(h_w, w_hh, e_w, o1_w, ldh,
                                                 whgh_bf, ew_bf, o1_bf, ldh_bf);
    pack_wih<<<dim3(3 * HID, 5), blk, 0, stream>>>(w_ih, wih_bf);
    prep_small<<<dim3(1), blk, 0, stream>>>(pal_in, gin_bf, h_b, b_hh, bias_cat);
    gemm_bf<0><<<dim3(2, 32), blk, 0, stream>>>(
        ldh_bf, HID, whgh_bf, HID, bias_cat, hgh, 4 * HID, BAT, HID,
        nullptr, 0, nullptr, nullptr);
    f2b_kernel<<<dim3((SEQ * BAT * HID) / 2048), blk, 0, stream>>>(
        enc, enc_bf, (size_t)SEQ * BAT * HID);
    gemm_bf<1><<<dim3(512, 8), blk, 0, stream>>>(
        enc_bf, HID, ew_bf, HID, e_b, nullptr, 0, SEQ * BAT, HID,
        hgh, 4 * HID, en_w, epart);
    softmax_context<<<dim3(256), blk, 0, stream>>>(
        epart, 8, enc_bf, out_att, out_ctx, gin_bf);
    gemm_bf<0><<<dim3(2, 24), blk, 0, stream>>>(
        gin_bf, 1088, wih_bf, 1088, b_ih, gi, 3 * HID, BAT, 1088,
        nullptr, 0, nullptr, nullptr);
    gru_combine<<<dim3(1024), blk, 0, stream>>>(gi, hgh + HID, 4 * HID, ldh, out_hid, hid_bf);
    gemm_bf<2><<<dim3(2, 8), blk, 0, stream>>>(
        hid_bf, HID, o1_bf, HID, o1_b, x1, HID, BAT, HID,
        nullptr, 0, nullptr, nullptr);
    bn_stats<<<dim3(4), blk, 0, stream>>>(x1, bnw, bnb, sj, tj);
    palette_kernel<<<dim3(256), blk, 0, stream>>>(x1, sj, tj, o2_w, o2_b, out_pal);
  } else {
    // -------- tier 3: fp32 fallback --------
    char* q = p0;
    auto carve2 = [&](size_t bytes) { char* r = q; q += (bytes + 255) & ~(size_t)255; return r; };
    float* hws2   = (float*)carve2((size_t)BAT * HID * 4);
    float* epart2 = (float*)carve2((size_t)8 * SEQ * BAT * 4);
    float* wsm2   = (float*)carve2((size_t)SEQ * BAT * 4);
    float* gin2   = (float*)carve2((size_t)BAT * 1088 * 4);
    float* gi2    = (float*)carve2((size_t)BAT * 3 * HID * 4);
    float* gh2    = (float*)carve2((size_t)BAT * 3 * HID * 4);
    float* x12    = (float*)carve2((size_t)BAT * HID * 4);
    float* sj2    = (float*)carve2((size_t)HID * 4);
    float* tj2    = (float*)carve2((size_t)HID * 4);

    gemm_bt<0, false><<<dim3(2, 8), blk, 0, stream>>>(
        ldh, HID, h_w, HID, HID, h_b, hws2, HID, BAT, HID, nullptr, nullptr, nullptr);
    gemm_bt<1, false><<<dim3(512, 8), blk, 0, stream>>>(
        enc, HID, e_w, HID, HID, e_b, nullptr, 0, SEQ * BAT, HID, hws2, en_w, epart2);
    gemm_bt<0, false><<<dim3(2, 24), blk, 0, stream>>>(
        ldh, HID, w_hh, HID, HID, b_hh, gh2, 3 * HID, BAT, HID, nullptr, nullptr, nullptr);
    softmax_kernel<<<dim3(256), blk, 0, stream>>>(epart2, 8, wsm2, out_att);
    prep_gin<<<dim3(1), blk, 0, stream>>>(pal_in, gin2);
    context_kernel<<<dim3(256, 4), blk, 0, stream>>>(enc, wsm2, out_ctx, gin2);
    gemm_bt<0, true><<<dim3(2, 24), blk, 0, stream>>>(
        gin2, 1088, w_ih, 1027, 1027, b_ih, gi2, 3 * HID, BAT, 1088, nullptr, nullptr, nullptr);
    gru_combine<<<dim3(1024), blk, 0, stream>>>(gi2, gh2, 3 * HID, ldh, out_hid, nullptr);
    gemm_bt<2, false><<<dim3(2, 8), blk, 0, stream>>>(
        out_hid, HID, o1_w, HID, HID, o1_b, x12, HID, BAT, HID, nullptr, nullptr, nullptr);
    bn_stats<<<dim3(4), blk, 0, stream>>>(x12, bnw, bnb, sj2, tj2);
    palette_kernel<<<dim3(256), blk, 0, stream>>>(x12, sj2, tj2, o2_w, o2_b, out_pal);
  }
}

// Round 11
// 286.789 us; speedup vs baseline: 1.0351x; 1.0351x over previous
//
#include <hip/hip_runtime.h>
#include <hip/hip_bf16.h>
#include <cstdint>

#define HID 1024
#define PAL 3
#define SEQ 256
#define BAT 256
#define BNEPS 1e-5f

#define NB_ENC 32768
#define NB_CW  2688
#define NB_EW8 512
#define NB_WIH 3072

typedef __attribute__((ext_vector_type(8))) short short8;
typedef __attribute__((ext_vector_type(2))) float floatx2;
typedef __attribute__((ext_vector_type(4))) float floatx4;
typedef __attribute__((ext_vector_type(8))) int int8v;

__device__ __forceinline__ ushort f2b(float f) {
  union { float f; uint32_t u; } v; v.f = f;
  uint32_t r = (v.u + 0x7FFFu + ((v.u >> 16) & 1u)) >> 16;
  return (ushort)r;
}
__device__ __forceinline__ float b2f(ushort u) {
  union { uint32_t u; float f; } v; v.u = ((uint32_t)u) << 16; return v.f;
}
__device__ __forceinline__ void gl_lds16(const ushort* g, ushort* l) {
  __builtin_amdgcn_global_load_lds(
      (const __attribute__((address_space(1))) void*)g,
      (__attribute__((address_space(3))) void*)l, 16, 0, 0);
}
__device__ __forceinline__ void gl_lds16b(const unsigned char* g, unsigned char* l) {
  __builtin_amdgcn_global_load_lds(
      (const __attribute__((address_space(1))) void*)g,
      (__attribute__((address_space(3))) void*)l, 16, 0, 0);
}

// ============ fp8 MX energy GEMM (128^2, 2-phase, T2 swizzle, K=128/MFMA) ============
// 1D grid 4096 with XCD-aware mapping (r8/r9-measured best): rt=(fid&7)+8*(fid>>6),
// ct=(fid>>3)&7 — all 8 col-tiles of a row-tile share fid%8 (same XCD under
// round-robin) so the A row-tile fills ONE L2 instead of eight.
__global__ __launch_bounds__(256, 2)
void gemm_fp8_energy(const unsigned char* __restrict__ A, const unsigned char* __restrict__ Bt,
                     const float* __restrict__ e_b, const float* __restrict__ hws, int ldh,
                     const float* __restrict__ enw, float* __restrict__ epart, int M)
{
  __shared__ unsigned char As[128 * 128];
  __shared__ unsigned char Bs[128 * 128];
  __shared__ float ep[2][128];

  const int tid = threadIdx.x;
  const int lane = tid & 63;
  const int wave = tid >> 6;
  const int l15 = lane & 15;
  const int s = lane >> 4;
  const int wr = (wave >> 1) * 64;
  const int wc = (wave & 1) * 64;

  const int fid = blockIdx.x;
  const int rt = (fid & 7) + ((fid >> 6) << 3);
  const int ct = (fid >> 3) & 7;
  const int row0 = rt * 128;
  const int col0 = ct * 128;

  floatx4 acc[4][4] = {};

  for (int kt = 0; kt < 1024; kt += 128) {
#pragma unroll
    for (int i = 0; i < 4; ++i) {
      int chunk = i * 256 + tid;
      int r = chunk >> 3, c8 = chunk & 7;
      int sc = (c8 ^ (r & 7)) << 4;
      gl_lds16b(A + (size_t)(row0 + r) * 1024 + kt + sc,
                As + (size_t)(i * 256 + wave * 64) * 16);
      gl_lds16b(Bt + (size_t)(col0 + r) * 1024 + kt + sc,
                Bs + (size_t)(i * 256 + wave * 64) * 16);
    }
    __syncthreads();
    int8v af[4], bf[4];
#pragma unroll
    for (int mi = 0; mi < 4; ++mi) {
      int row = wr + mi * 16 + l15;
      int4 lo = *reinterpret_cast<const int4*>(&As[row * 128 + (((2 * s) ^ (row & 7)) << 4)]);
      int4 hi = *reinterpret_cast<const int4*>(&As[row * 128 + (((2 * s + 1) ^ (row & 7)) << 4)]);
      int8v v; v[0] = lo.x; v[1] = lo.y; v[2] = lo.z; v[3] = lo.w;
      v[4] = hi.x; v[5] = hi.y; v[6] = hi.z; v[7] = hi.w;
      af[mi] = v;
    }
#pragma unroll
    for (int ni = 0; ni < 4; ++ni) {
      int row = wc + ni * 16 + l15;
      int4 lo = *reinterpret_cast<const int4*>(&Bs[row * 128 + (((2 * s) ^ (row & 7)) << 4)]);
      int4 hi = *reinterpret_cast<const int4*>(&Bs[row * 128 + (((2 * s + 1) ^ (row & 7)) << 4)]);
      int8v v; v[0] = lo.x; v[1] = lo.y; v[2] = lo.z; v[3] = lo.w;
      v[4] = hi.x; v[5] = hi.y; v[6] = hi.z; v[7] = hi.w;
      bf[ni] = v;
    }
#pragma unroll
    for (int mi = 0; mi < 4; ++mi)
#pragma unroll
      for (int ni = 0; ni < 4; ++ni)
        acc[mi][ni] = __builtin_amdgcn_mfma_scale_f32_16x16x128_f8f6f4(
            af[mi], bf[ni], acc[mi][ni], 0, 0, 0, 0x7F7F7F7F, 0, 0x7F7F7F7F);
    __syncthreads();
  }

  float rs[4][4];
#pragma unroll
  for (int mi = 0; mi < 4; ++mi) {
#pragma unroll
    for (int q = 0; q < 4; ++q) {
      int m = row0 + wr + mi * 16 + (lane >> 4) * 4 + q;
      int b = m & (BAT - 1);
      float v = 0.f;
#pragma unroll
      for (int ni = 0; ni < 4; ++ni) {
        int cg = col0 + wc + ni * 16 + l15;
        float e = acc[mi][ni][q] * 0.015625f + e_b[cg] + hws[(size_t)b * ldh + cg];
        v += enw[cg] * (1.f / (1.f + __expf(-e)));
      }
#pragma unroll
      for (int o = 1; o < 16; o <<= 1) v += __shfl_xor(v, o);
      rs[mi][q] = v;
    }
  }
  if (l15 == 0) {
#pragma unroll
    for (int mi = 0; mi < 4; ++mi)
#pragma unroll
      for (int q = 0; q < 4; ++q)
        ep[wave & 1][wr + mi * 16 + (lane >> 4) * 4 + q] = rs[mi][q];
  }
  __syncthreads();
  if (tid < 128)
    epart[(size_t)ct * M + row0 + tid] = ep[0][tid] + ep[1][tid];
}

// ---------------- bf16 GEMM, m97 structure + T2 swizzle ----------------
template<int EPI>
__global__ __launch_bounds__(256, 2)
void gemm_bf(const ushort* __restrict__ A, int lda,
             const ushort* __restrict__ Bt, int ldb,
             const float* __restrict__ bias,
             float* __restrict__ C, int ldc,
             int M, int K,
             const float* __restrict__ hws, int ldh,
             const float* __restrict__ enw,
             float* __restrict__ epart)
{
  __shared__ ushort As[128 * 64];
  __shared__ ushort Bs[128 * 64];
  __shared__ float ep[2][128];

  const int tid = threadIdx.x;
  const int lane = tid & 63;
  const int wave = tid >> 6;
  const int l15 = lane & 15;
  const int wr = (wave >> 1) * 64;
  const int wc = (wave & 1) * 64;
  const int row0 = blockIdx.x * 128;
  const int col0 = blockIdx.y * 128;

  floatx4 acc[4][4] = {};

  for (int kt = 0; kt < K; kt += 64) {
#pragma unroll
    for (int i = 0; i < 4; ++i) {
      int chunk = i * 256 + tid;
      int r = chunk >> 3, c8 = chunk & 7;
      int sc = (c8 ^ (r & 7)) << 3;
      gl_lds16(A + (size_t)(row0 + r) * lda + kt + sc,
               (ushort*)As + (size_t)(i * 256 + wave * 64) * 8);
      gl_lds16(Bt + (size_t)(col0 + r) * ldb + kt + sc,
               (ushort*)Bs + (size_t)(i * 256 + wave * 64) * 8);
    }
    __syncthreads();
#pragma unroll
    for (int kk = 0; kk < 2; ++kk) {
      const int kc = (lane >> 4) + kk * 4;
      short8 af[4], bf[4];
#pragma unroll
      for (int mi = 0; mi < 4; ++mi) {
        int row = wr + mi * 16 + l15;
        af[mi] = *reinterpret_cast<const short8*>(&As[row * 64 + ((kc ^ (row & 7)) << 3)]);
      }
#pragma unroll
      for (int ni = 0; ni < 4; ++ni) {
        int row = wc + ni * 16 + l15;
        bf[ni] = *reinterpret_cast<const short8*>(&Bs[row * 64 + ((kc ^ (row & 7)) << 3)]);
      }
#pragma unroll
      for (int mi = 0; mi < 4; ++mi)
#pragma unroll
        for (int ni = 0; ni < 4; ++ni)
          acc[mi][ni] = __builtin_amdgcn_mfma_f32_16x16x32_bf16(af[mi], bf[ni], acc[mi][ni], 0, 0, 0);
    }
    __syncthreads();
  }

  if (EPI == 0 || EPI == 2) {
#pragma unroll
    for (int mi = 0; mi < 4; ++mi) {
      int rloc = wr + mi * 16 + (lane >> 4) * 4;
#pragma unroll
      for (int ni = 0; ni < 4; ++ni) {
        int cg = col0 + wc + ni * 16 + l15;
        float bv = bias ? bias[cg] : 0.f;
#pragma unroll
        for (int q = 0; q < 4; ++q) {
          float v = acc[mi][ni][q] + bv;
          if (EPI == 2) v = fmaxf(v, 0.f);
          C[(size_t)(row0 + rloc + q) * ldc + cg] = v;
        }
      }
    }
  } else {
    float rs[4][4];
#pragma unroll
    for (int mi = 0; mi < 4; ++mi) {
#pragma unroll
      for (int q = 0; q < 4; ++q) {
        int m = row0 + wr + mi * 16 + (lane >> 4) * 4 + q;
        int b = m & (BAT - 1);
        float v = 0.f;
#pragma unroll
        for (int ni = 0; ni < 4; ++ni) {
          int cg = col0 + wc + ni * 16 + l15;
          float e = acc[mi][ni][q] + bias[cg] + hws[(size_t)b * ldh + cg];
          v += enw[cg] * (1.f / (1.f + __expf(-e)));
        }
#pragma unroll
        for (int o = 1; o < 16; o <<= 1) v += __shfl_xor(v, o);
        rs[mi][q] = v;
      }
    }
    if (l15 == 0) {
#pragma unroll
      for (int mi = 0; mi < 4; ++mi)
#pragma unroll
        for (int q = 0; q < 4; ++q)
          ep[wave & 1][wr + mi * 16 + (lane >> 4) * 4 + q] = rs[mi][q];
    }
    __syncthreads();
    if (tid < 128)
      epart[(size_t)blockIdx.y * M + row0 + tid] = ep[0][tid] + ep[1][tid];
  }
}

// ---------------- fp32-input GEMM (deep fallback only) ----------------
template<int EPI, bool GUARDB>
__global__ __launch_bounds__(256, 2)
void gemm_bt(const float* __restrict__ A, int lda,
             const float* __restrict__ Bt, int ldb, int Kb,
             const float* __restrict__ bias,
             float* __restrict__ C, int ldc,
             int M, int K,
             const float* __restrict__ hws,
             const float* __restrict__ enw,
             float* __restrict__ epart)
{
  __shared__ ushort As[128 * 72];
  __shared__ ushort Bs[128 * 72];
  __shared__ float ep[2][128];

  const int tid = threadIdx.x;
  const int lane = tid & 63;
  const int wave = tid >> 6;
  const int wr = (wave >> 1) * 64;
  const int wc = (wave & 1) * 64;
  const int row0 = blockIdx.x * 128;
  const int col0 = blockIdx.y * 128;
  const int rb = tid >> 4;
  const int c4 = tid & 15;

  floatx4 acc[4][4] = {};

  for (int kt = 0; kt < K; kt += 64) {
    float4 aL[8], bL[8];
#pragma unroll
    for (int it = 0; it < 8; ++it) {
      int r = it * 16 + rb;
      aL[it] = *reinterpret_cast<const float4*>(A + (size_t)(row0 + r) * lda + kt + c4 * 4);
      if (GUARDB) {
        int k0 = kt + c4 * 4;
        const float* bp = Bt + (size_t)(col0 + r) * ldb;
        bL[it].x = (k0 + 0 < Kb) ? bp[k0 + 0] : 0.f;
        bL[it].y = (k0 + 1 < Kb) ? bp[k0 + 1] : 0.f;
        bL[it].z = (k0 + 2 < Kb) ? bp[k0 + 2] : 0.f;
        bL[it].w = (k0 + 3 < Kb) ? bp[k0 + 3] : 0.f;
      } else {
        bL[it] = *reinterpret_cast<const float4*>(Bt + (size_t)(col0 + r) * ldb + kt + c4 * 4);
      }
    }
    __syncthreads();
#pragma unroll
    for (int it = 0; it < 8; ++it) {
      int r = it * 16 + rb;
      ushort4 av = make_ushort4(f2b(aL[it].x), f2b(aL[it].y), f2b(aL[it].z), f2b(aL[it].w));
      ushort4 bv = make_ushort4(f2b(bL[it].x), f2b(bL[it].y), f2b(bL[it].z), f2b(bL[it].w));
      *reinterpret_cast<ushort4*>(&As[r * 72 + c4 * 4]) = av;
      *reinterpret_cast<ushort4*>(&Bs[r * 72 + c4 * 4]) = bv;
    }
    __syncthreads();
#pragma unroll
    for (int kk = 0; kk < 2; ++kk) {
      const int ko = (lane >> 4) * 8 + kk * 32;
      short8 af[4], bf[4];
#pragma unroll
      for (int mi = 0; mi < 4; ++mi)
        af[mi] = *reinterpret_cast<const short8*>(&As[(wr + mi * 16 + (lane & 15)) * 72 + ko]);
#pragma unroll
      for (int ni = 0; ni < 4; ++ni)
        bf[ni] = *reinterpret_cast<const short8*>(&Bs[(wc + ni * 16 + (lane & 15)) * 72 + ko]);
#pragma unroll
      for (int mi = 0; mi < 4; ++mi)
#pragma unroll
        for (int ni = 0; ni < 4; ++ni)
          acc[mi][ni] = __builtin_amdgcn_mfma_f32_16x16x32_bf16(af[mi], bf[ni], acc[mi][ni], 0, 0, 0);
    }
  }

  if (EPI == 0 || EPI == 2) {
#pragma unroll
    for (int mi = 0; mi < 4; ++mi) {
      int rloc = wr + mi * 16 + (lane >> 4) * 4;
#pragma unroll
      for (int ni = 0; ni < 4; ++ni) {
        int cg = col0 + wc + ni * 16 + (lane & 15);
        float bv = bias ? bias[cg] : 0.f;
#pragma unroll
        for (int q = 0; q < 4; ++q) {
          float v = acc[mi][ni][q] + bv;
          if (EPI == 2) v = fmaxf(v, 0.f);
          C[(size_t)(row0 + rloc + q) * ldc + cg] = v;
        }
      }
    }
  } else {
    float rs[4][4];
#pragma unroll
    for (int mi = 0; mi < 4; ++mi) {
#pragma unroll
      for (int q = 0; q < 4; ++q) {
        int m = row0 + wr + mi * 16 + (lane >> 4) * 4 + q;
        int b = m & (BAT - 1);
        float v = 0.f;
#pragma unroll
        for (int ni = 0; ni < 4; ++ni) {
          int cg = col0 + wc + ni * 16 + (lane & 15);
          float e = acc[mi][ni][q] + bias[cg] + hws[(size_t)b * HID + cg];
          float sg = 1.f / (1.f + __expf(-e));
          v += sg * enw[cg];
        }
#pragma unroll
        for (int o = 1; o < 16; o <<= 1) v += __shfl_xor(v, o);
        rs[mi][q] = v;
      }
    }
    if ((lane & 15) == 0) {
#pragma unroll
      for (int mi = 0; mi < 4; ++mi)
#pragma unroll
        for (int q = 0; q < 4; ++q)
          ep[wave & 1][wr + mi * 16 + (lane >> 4) * 4 + q] = rs[mi][q];
    }
    __syncthreads();
    if (tid < 128)
      epart[(size_t)blockIdx.y * M + row0 + tid] = ep[0][tid] + ep[1][tid];
  }
}

// ---------------- fused prep megakernel (tier 1; no dead ew_bf conversion) ----------
__global__ __launch_bounds__(256)
void megaprep(const float* __restrict__ enc,
              const float* __restrict__ hw, const float* __restrict__ whh,
              const float* __restrict__ ew, const float* __restrict__ o1w,
              const float* __restrict__ ldh, const float* __restrict__ wih,
              const float* __restrict__ pal,
              const float* __restrict__ h_b, const float* __restrict__ b_hh,
              unsigned char* __restrict__ enc8,
              ushort* __restrict__ whgh,
              ushort* __restrict__ o1b, ushort* __restrict__ ldhb,
              unsigned char* __restrict__ ew8, ushort* __restrict__ wihb,
              ushort* __restrict__ ginb, float* __restrict__ bias_cat)
{
  const int blk = blockIdx.x;
  const int tid = threadIdx.x;
  if (blk < NB_ENC) {
    size_t i = (size_t)blk * 2048 + (size_t)tid * 8;
    float4 a = *reinterpret_cast<const float4*>(enc + i);
    float4 b = *reinterpret_cast<const float4*>(enc + i + 4);
    int w01 = __builtin_amdgcn_cvt_pk_fp8_f32(a.x, a.y, 0, false);
    int w03 = __builtin_amdgcn_cvt_pk_fp8_f32(a.z, a.w, w01, true);
    int w45 = __builtin_amdgcn_cvt_pk_fp8_f32(b.x, b.y, 0, false);
    int w47 = __builtin_amdgcn_cvt_pk_fp8_f32(b.z, b.w, w45, true);
    int2 pk; pk.x = w03; pk.y = w47;
    *reinterpret_cast<int2*>(enc8 + i) = pk;
  } else if (blk < NB_ENC + NB_CW) {
    int cw = blk - NB_ENC;
    const float* src; ushort* dst; size_t off;
    if (cw < 512)        { src = hw;  dst = whgh;            off = (size_t)cw * 2048; }
    else if (cw < 2048)  { src = whh; dst = whgh + 1048576;  off = (size_t)(cw - 512) * 2048; }
    else if (cw < 2560)  { src = o1w; dst = o1b;             off = (size_t)(cw - 2048) * 2048; }
    else                 { src = ldh; dst = ldhb;            off = (size_t)(cw - 2560) * 2048; }
    size_t i = off + (size_t)tid * 8;
    float4 a = *reinterpret_cast<const float4*>(src + i);
    float4 b = *reinterpret_cast<const float4*>(src + i + 4);
    ushort o[8] = {f2b(a.x), f2b(a.y), f2b(a.z), f2b(a.w),
                   f2b(b.x), f2b(b.y), f2b(b.z), f2b(b.w)};
    *reinterpret_cast<short8*>(dst + i) = *reinterpret_cast<short8*>(o);
  } else if (blk < NB_ENC + NB_CW + NB_EW8) {
    size_t i = (size_t)(blk - NB_ENC - NB_CW) * 2048 + (size_t)tid * 8;
    float4 a = *reinterpret_cast<const float4*>(ew + i);
    float4 b = *reinterpret_cast<const float4*>(ew + i + 4);
    int w01 = __builtin_amdgcn_cvt_pk_fp8_f32(a.x * 64.f, a.y * 64.f, 0, false);
    int w03 = __builtin_amdgcn_cvt_pk_fp8_f32(a.z * 64.f, a.w * 64.f, w01, true);
    int w45 = __builtin_amdgcn_cvt_pk_fp8_f32(b.x * 64.f, b.y * 64.f, 0, false);
    int w47 = __builtin_amdgcn_cvt_pk_fp8_f32(b.z * 64.f, b.w * 64.f, w45, true);
    int2 pk; pk.x = w03; pk.y = w47;
    *reinterpret_cast<int2*>(ew8 + i) = pk;
  } else if (blk < NB_ENC + NB_CW + NB_EW8 + NB_WIH) {
    int r = blk - NB_ENC - NB_CW - NB_EW8;
    for (int c = tid; c < 1088; c += 256) {
      ushort v = 0;
      if (c < 1024)      v = f2b(wih[(size_t)r * 1027 + 3 + c]);
      else if (c < 1027) v = f2b(wih[(size_t)r * 1027 + (c - 1024)]);
      wihb[(size_t)r * 1088 + c] = v;
    }
  } else {
    ginb[tid * 1088 + 1024] = f2b(pal[tid * 3 + 0]);
    ginb[tid * 1088 + 1025] = f2b(pal[tid * 3 + 1]);
    ginb[tid * 1088 + 1026] = f2b(pal[tid * 3 + 2]);
    for (int k = 1027; k < 1088; ++k) ginb[tid * 1088 + k] = 0;
    for (int j = tid; j < 4096; j += 256) bias_cat[j] = (j < 1024) ? h_b[j] : b_hh[j - 1024];
  }
}

// ------- merged softmax + context, fp8 enc input (tier 1; one block per batch) -------
__global__ void softmax_context_fp8(const float* __restrict__ epart, int ntiles,
                                    const unsigned char* __restrict__ enc8,
                                    float* __restrict__ att, float* __restrict__ ctx,
                                    ushort* __restrict__ ginb) {
  int b = blockIdx.x, s = threadIdx.x;
  __shared__ float wl[256];
  __shared__ float rm[4], rsum[4];
  float e = 0.f;
  for (int nt = 0; nt < ntiles; ++nt) e += epart[(size_t)nt * (SEQ * BAT) + s * BAT + b];
  float m = e;
  for (int o = 1; o < 64; o <<= 1) m = fmaxf(m, __shfl_xor(m, o));
  if ((s & 63) == 0) rm[s >> 6] = m;
  __syncthreads();
  m = fmaxf(fmaxf(rm[0], rm[1]), fmaxf(rm[2], rm[3]));
  float ex = __expf(e - m);
  float sum = ex;
  for (int o = 1; o < 64; o <<= 1) sum += __shfl_xor(sum, o);
  if ((s & 63) == 0) rsum[s >> 6] = sum;
  __syncthreads();
  sum = rsum[0] + rsum[1] + rsum[2] + rsum[3];
  float w = ex / sum;
  att[b * SEQ + s] = w;
  wl[s] = w;
  __syncthreads();
  int h0 = s * 4;
  const unsigned char* ep = enc8 + (size_t)b * HID + h0;
  float c0 = 0.f, c1 = 0.f, c2 = 0.f, c3 = 0.f;
#pragma unroll 8
  for (int s2 = 0; s2 < SEQ; ++s2) {
    unsigned int v = *reinterpret_cast<const unsigned int*>(ep + (size_t)s2 * BAT * HID);
    floatx2 lo = __builtin_amdgcn_cvt_pk_f32_fp8(v, false);
    floatx2 hi = __builtin_amdgcn_cvt_pk_f32_fp8(v, true);
    float ww = wl[s2];
    c0 += ww * lo[0]; c1 += ww * lo[1]; c2 += ww * hi[0]; c3 += ww * hi[1];
  }
  float4 o = {c0, c1, c2, c3};
  *reinterpret_cast<float4*>(ctx + (size_t)b * HID + h0) = o;
  ushort g[4] = {f2b(c0), f2b(c1), f2b(c2), f2b(c3)};
  *reinterpret_cast<ushort4*>(ginb + (size_t)b * 1088 + h0) = *reinterpret_cast<ushort4*>(g);
}

// ---------------- merged softmax + context, bf16 enc (tier 2) ----------------
__global__ void softmax_context(const float* __restrict__ epart, int ntiles,
                                const ushort* __restrict__ encb,
                                float* __restrict__ att, float* __restrict__ ctx,
                                ushort* __restrict__ ginb) {
  int b = blockIdx.x, s = threadIdx.x;
  __shared__ float wl[256];
  __shared__ float rm[4], rsum[4];
  float e = 0.f;
  for (int nt = 0; nt < ntiles; ++nt) e += epart[(size_t)nt * (SEQ * BAT) + s * BAT + b];
  float m = e;
  for (int o = 1; o < 64; o <<= 1) m = fmaxf(m, __shfl_xor(m, o));
  if ((s & 63) == 0) rm[s >> 6] = m;
  __syncthreads();
  m = fmaxf(fmaxf(rm[0], rm[1]), fmaxf(rm[2], rm[3]));
  float ex = __expf(e - m);
  float sum = ex;
  for (int o = 1; o < 64; o <<= 1) sum += __shfl_xor(sum, o);
  if ((s & 63) == 0) rsum[s >> 6] = sum;
  __syncthreads();
  sum = rsum[0] + rsum[1] + rsum[2] + rsum[3];
  float w = ex / sum;
  att[b * SEQ + s] = w;
  wl[s] = w;
  __syncthreads();
  int h0 = s * 4;
  const ushort* ep = encb + (size_t)b * HID + h0;
  float c0 = 0.f, c1 = 0.f, c2 = 0.f, c3 = 0.f;
#pragma unroll 8
  for (int s2 = 0; s2 < SEQ; ++s2) {
    ushort4 v = *reinterpret_cast<const ushort4*>(ep + (size_t)s2 * BAT * HID);
    float ww = wl[s2];
    c0 += ww * b2f(v.x); c1 += ww * b2f(v.y); c2 += ww * b2f(v.z); c3 += ww * b2f(v.w);
  }
  float4 o = {c0, c1, c2, c3};
  *reinterpret_cast<float4*>(ctx + (size_t)b * HID + h0) = o;
  ushort g[4] = {f2b(c0), f2b(c1), f2b(c2), f2b(c3)};
  *reinterpret_cast<ushort4*>(ginb + (size_t)b * 1088 + h0) = *reinterpret_cast<ushort4*>(g);
}

// ---------------- legacy kernels (fallback tiers) ----------------
__global__ void f2b_kernel(const float* __restrict__ in, ushort* __restrict__ out, size_t n) {
  size_t i = ((size_t)blockIdx.x * 256 + threadIdx.x) * 8;
  if (i + 8 > n) return;
  float4 a = *reinterpret_cast<const float4*>(in + i);
  float4 b = *reinterpret_cast<const float4*>(in + i + 4);
  ushort o[8] = {f2b(a.x), f2b(a.y), f2b(a.z), f2b(a.w),
                 f2b(b.x), f2b(b.y), f2b(b.z), f2b(b.w)};
  *reinterpret_cast<short8*>(out + i) = *reinterpret_cast<short8*>(o);
}

__global__ void conv_weights(const float* __restrict__ hw, const float* __restrict__ whh,
                             const float* __restrict__ ew, const float* __restrict__ o1w,
                             const float* __restrict__ ldh,
                             ushort* __restrict__ whgh, ushort* __restrict__ ewb,
                             ushort* __restrict__ o1b, ushort* __restrict__ ldhb) {
  int blk = blockIdx.x;
  const float* src; ushort* dst; size_t off;
  if (blk < 512)        { src = hw;  dst = whgh;            off = (size_t)blk * 2048; }
  else if (blk < 2048)  { src = whh; dst = whgh + 1048576;  off = (size_t)(blk - 512) * 2048; }
  else if (blk < 2560)  { src = ew;  dst = ewb;             off = (size_t)(blk - 2048) * 2048; }
  else if (blk < 3072)  { src = o1w; dst = o1b;             off = (size_t)(blk - 2560) * 2048; }
  else                  { src = ldh; dst = ldhb;            off = (size_t)(blk - 3072) * 2048; }
  size_t i = off + (size_t)threadIdx.x * 8;
  float4 a = *reinterpret_cast<const float4*>(src + i);
  float4 b = *reinterpret_cast<const float4*>(src + i + 4);
  ushort o[8] = {f2b(a.x), f2b(a.y), f2b(a.z), f2b(a.w),
                 f2b(b.x), f2b(b.y), f2b(b.z), f2b(b.w)};
  *reinterpret_cast<short8*>(dst + i) = *reinterpret_cast<short8*>(o);
}

__global__ void pack_wih(const float* __restrict__ in, ushort* __restrict__ out) {
  int r = blockIdx.x;
  int c = blockIdx.y * 256 + threadIdx.x;
  if (c < 1088) {
    ushort v = 0;
    if (c < 1024)      v = f2b(in[(size_t)r * 1027 + 3 + c]);
    else if (c < 1027) v = f2b(in[(size_t)r * 1027 + (c - 1024)]);
    out[(size_t)r * 1088 + c] = v;
  }
}

__global__ void softmax_kernel(const float* __restrict__ epart, int ntiles,
                               float* __restrict__ wsm, float* __restrict__ att) {
  int b = blockIdx.x, s = threadIdx.x;
  float e = 0.f;
  for (int nt = 0; nt < ntiles; ++nt) e += epart[(size_t)nt * (SEQ * BAT) + s * BAT + b];
  float m = e;
  for (int o = 1; o < 64; o <<= 1) m = fmaxf(m, __shfl_xor(m, o));
  __shared__ float rm[4], rsum[4];
  if ((s & 63) == 0) rm[s >> 6] = m;
  __syncthreads();
  m = fmaxf(fmaxf(rm[0], rm[1]), fmaxf(rm[2], rm[3]));
  float ex = __expf(e - m);
  float sum = ex;
  for (int o = 1; o < 64; o <<= 1) sum += __shfl_xor(sum, o);
  if ((s & 63) == 0) rsum[s >> 6] = sum;
  __syncthreads();
  sum = rsum[0] + rsum[1] + rsum[2] + rsum[3];
  float w = ex / sum;
  wsm[s * BAT + b] = w;
  att[b * SEQ + s] = w;
}

__global__ void prep_small(const float* __restrict__ pal, ushort* __restrict__ ginb,
                           const float* __restrict__ h_b, const float* __restrict__ b_hh,
                           float* __restrict__ bias_cat) {
  int t = threadIdx.x;
  ginb[t * 1088 + 1024] = f2b(pal[t * 3 + 0]);
  ginb[t * 1088 + 1025] = f2b(pal[t * 3 + 1]);
  ginb[t * 1088 + 1026] = f2b(pal[t * 3 + 2]);
  for (int k = 1027; k < 1088; ++k) ginb[t * 1088 + k] = 0;
  for (int j = t; j < 4096; j += 256) bias_cat[j] = (j < 1024) ? h_b[j] : b_hh[j - 1024];
}

__global__ void prep_gin(const float* __restrict__ pal, float* __restrict__ gin) {
  int b = threadIdx.x;
  gin[b * 1088 + 0] = pal[b * 3 + 0];
  gin[b * 1088 + 1] = pal[b * 3 + 1];
  gin[b * 1088 + 2] = pal[b * 3 + 2];
  for (int k = 1027; k < 1088; ++k) gin[b * 1088 + k] = 0.f;
}

__global__ void context_kernel(const float* __restrict__ enc, const float* __restrict__ wsm,
                               float* __restrict__ ctx, float* __restrict__ gin) {
  int b = blockIdx.x, hc = blockIdx.y, t = threadIdx.x;
  __shared__ float wl[256];
  wl[t] = wsm[t * BAT + b];
  __syncthreads();
  int h = hc * 256 + t;
  const float* ep = enc + (size_t)b * HID + h;
  float c = 0.f;
#pragma unroll 8
  for (int s = 0; s < SEQ; ++s) c += wl[s] * ep[(size_t)s * BAT * HID];
  ctx[(size_t)b * HID + h] = c;
  gin[b * 1088 + 3 + h] = c;
}

__global__ void gru_combine(const float* __restrict__ gi, const float* __restrict__ gh, int ghs,
                            const float* __restrict__ hprev, float* __restrict__ hout,
                            ushort* __restrict__ hb) {
  int idx = blockIdx.x * 256 + threadIdx.x;
  int b = idx >> 10, j = idx & 1023;
  size_t gib = (size_t)b * 3 * HID;
  size_t ghb = (size_t)b * ghs;
  float ir = gi[gib + j], iz = gi[gib + HID + j], in_ = gi[gib + 2 * HID + j];
  float hr = gh[ghb + j], hz = gh[ghb + HID + j], hn = gh[ghb + 2 * HID + j];
  float r = 1.f / (1.f + __expf(-(ir + hr)));
  float z = 1.f / (1.f + __expf(-(iz + hz)));
  float n = tanhf(in_ + r * hn);
  float v = (1.f - z) * n + z * hprev[idx];
  hout[idx] = v;
  if (hb) hb[idx] = f2b(v);
}

__global__ void bn_stats(const float* __restrict__ x1, const float* __restrict__ bnw,
                         const float* __restrict__ bnb, float* __restrict__ sj,
                         float* __restrict__ tj) {
  int j = blockIdx.x * 256 + threadIdx.x;
  float s = 0.f, ss = 0.f;
  for (int b = 0; b < BAT; ++b) {
    float x = x1[(size_t)b * HID + j];
    s += x; ss += x * x;
  }
  float mu = s * (1.f / BAT);
  float var = ss * (1.f / BAT) - mu * mu;
  float rstd = rsqrtf(var + BNEPS);
  float sc = bnw[j] * rstd;
  sj[j] = sc;
  tj[j] = bnb[j] - mu * sc;
}

__global__ void palette_kernel(const float* __restrict__ x1, const float* __restrict__ sj,
                               const float* __restrict__ tj, const float* __restrict__ w2,
                               const float* __restrict__ b2, float* __restrict__ outp) {
  int b = blockIdx.x, t = threadIdx.x;
  float p0 = 0.f, p1 = 0.f, p2 = 0.f;
  for (int j = t; j < HID; j += 256) {
    float xn = x1[(size_t)b * HID + j] * sj[j] + tj[j];
    p0 += xn * w2[j];
    p1 += xn * w2[HID + j];
    p2 += xn * w2[2 * HID + j];
  }
  for (int o = 1; o < 64; o <<= 1) {
    p0 += __shfl_xor(p0, o); p1 += __shfl_xor(p1, o); p2 += __shfl_xor(p2, o);
  }
  __shared__ float r0[4], r1[4], r2[4];
  int w = t >> 6;
  if ((t & 63) == 0) { r0[w] = p0; r1[w] = p1; r2[w] = p2; }
  __syncthreads();
  if (t == 0) {
    outp[b * 3 + 0] = r0[0] + r0[1] + r0[2] + r0[3] + b2[0];
    outp[b * 3 + 1] = r1[0] + r1[1] + r1[2] + r1[3] + b2[1];
    outp[b * 3 + 2] = r2[0] + r2[1] + r2[2] + r2[3] + b2[2];
  }
}

extern "C" void kernel_launch(void* const* d_in, const int* in_sizes, int n_in,
                              void* d_out, int out_size, void* d_ws, size_t ws_size,
                              hipStream_t stream) {
  const float* pal_in = (const float*)d_in[0];
  const float* ldh    = (const float*)d_in[1];
  const float* enc    = (const float*)d_in[2];
  const float* e_w    = (const float*)d_in[3];
  const float* e_b    = (const float*)d_in[4];
  const float* h_w    = (const float*)d_in[5];
  const float* h_b    = (const float*)d_in[6];
  const float* en_w   = (const float*)d_in[7];
  const float* w_ih   = (const float*)d_in[9];
  const float* w_hh   = (const float*)d_in[10];
  const float* b_ih   = (const float*)d_in[11];
  const float* b_hh   = (const float*)d_in[12];
  const float* o1_w   = (const float*)d_in[13];
  const float* o1_b   = (const float*)d_in[14];
  const float* bnw    = (const float*)d_in[15];
  const float* bnb    = (const float*)d_in[16];
  const float* o2_w   = (const float*)d_in[17];
  const float* o2_b   = (const float*)d_in[18];

  float* out = (float*)d_out;
  float* out_pal = out;
  float* out_ctx = out + BAT * PAL;
  float* out_hid = out_ctx + BAT * HID;
  float* out_att = out_hid + BAT * HID;

  dim3 blk(256);

  char* p0 = (char*)d_ws;
  char* p = p0;
  auto carve = [&](size_t bytes) { char* r = p; p += (bytes + 255) & ~(size_t)255; return r; };
  ushort* enc_bf  = (ushort*)carve((size_t)SEQ * BAT * HID * 2);
  ushort* whgh_bf = (ushort*)carve((size_t)4 * HID * HID * 2);
  ushort* ew_bf   = (ushort*)carve((size_t)HID * HID * 2);
  ushort* wih_bf  = (ushort*)carve((size_t)3 * HID * 1088 * 2);
  ushort* o1_bf   = (ushort*)carve((size_t)HID * HID * 2);
  ushort* ldh_bf  = (ushort*)carve((size_t)BAT * HID * 2);
  ushort* gin_bf  = (ushort*)carve((size_t)BAT * 1088 * 2);
  ushort* hid_bf  = (ushort*)carve((size_t)BAT * HID * 2);
  float* hgh      = (float*)carve((size_t)BAT * 4 * HID * 4);
  float* bias_cat = (float*)carve((size_t)4 * HID * 4);
  float* epart    = (float*)carve((size_t)8 * SEQ * BAT * 4);
  float* wsm      = (float*)carve((size_t)SEQ * BAT * 4);
  float* gi       = (float*)carve((size_t)BAT * 3 * HID * 4);
  float* x1       = (float*)carve((size_t)BAT * HID * 4);
  float* sj       = (float*)carve((size_t)HID * 4);
  float* tj       = (float*)carve((size_t)HID * 4);
  size_t need_mid = (size_t)(p - p0);
  unsigned char* enc8 = (unsigned char*)carve((size_t)SEQ * BAT * HID);
  unsigned char* ew8  = (unsigned char*)carve((size_t)HID * HID);
  size_t need_full = (size_t)(p - p0);

  if (ws_size >= need_full) {
    // -------- tier 1: fp8 MX energy + fp8 context, 1D XCD-remapped energy grid -----
    megaprep<<<dim3(NB_ENC + NB_CW + NB_EW8 + NB_WIH + 1), blk, 0, stream>>>(
        enc, h_w, w_hh, e_w, o1_w, ldh, w_ih, pal_in, h_b, b_hh,
        enc8, whgh_bf, o1_bf, ldh_bf, ew8, wih_bf, gin_bf, bias_cat);
    gemm_bf<0><<<dim3(2, 32), blk, 0, stream>>>(
        ldh_bf, HID, whgh_bf, HID, bias_cat, hgh, 4 * HID, BAT, HID,
        nullptr, 0, nullptr, nullptr);
    gemm_fp8_energy<<<dim3(4096), blk, 0, stream>>>(
        enc8, ew8, e_b, hgh, 4 * HID, en_w, epart, SEQ * BAT);
    softmax_context_fp8<<<dim3(256), blk, 0, stream>>>(
        epart, 8, enc8, out_att, out_ctx, gin_bf);
    gemm_bf<0><<<dim3(2, 24), blk, 0, stream>>>(
        gin_bf, 1088, wih_bf, 1088, b_ih, gi, 3 * HID, BAT, 1088,
        nullptr, 0, nullptr, nullptr);
    gru_combine<<<dim3(1024), blk, 0, stream>>>(gi, hgh + HID, 4 * HID, ldh, out_hid, hid_bf);
    gemm_bf<2><<<dim3(2, 8), blk, 0, stream>>>(
        hid_bf, HID, o1_bf, HID, o1_b, x1, HID, BAT, HID,
        nullptr, 0, nullptr, nullptr);
    bn_stats<<<dim3(4), blk, 0, stream>>>(x1, bnw, bnb, sj, tj);
    palette_kernel<<<dim3(256), blk, 0, stream>>>(x1, sj, tj, o2_w, o2_b, out_pal);
  } else if (ws_size >= need_mid) {
    // -------- tier 2: bf16 path --------
    conv_weights<<<dim3(3200), blk, 0, stream>>>(h_w, w_hh, e_w, o1_w, ldh,
                                                 whgh_bf, ew_bf, o1_bf, ldh_bf);
    pack_wih<<<dim3(3 * HID, 5), blk, 0, stream>>>(w_ih, wih_bf);
    prep_small<<<dim3(1), blk, 0, stream>>>(pal_in, gin_bf, h_b, b_hh, bias_cat);
    gemm_bf<0><<<dim3(2, 32), blk, 0, stream>>>(
        ldh_bf, HID, whgh_bf, HID, bias_cat, hgh, 4 * HID, BAT, HID,
        nullptr, 0, nullptr, nullptr);
    f2b_kernel<<<dim3((SEQ * BAT * HID) / 2048), blk, 0, stream>>>(
        enc, enc_bf, (size_t)SEQ * BAT * HID);
    gemm_bf<1><<<dim3(512, 8), blk, 0, stream>>>(
        enc_bf, HID, ew_bf, HID, e_b, nullptr, 0, SEQ * BAT, HID,
        hgh, 4 * HID, en_w, epart);
    softmax_context<<<dim3(256), blk, 0, stream>>>(
        epart, 8, enc_bf, out_att, out_ctx, gin_bf);
    gemm_bf<0><<<dim3(2, 24), blk, 0, stream>>>(
        gin_bf, 1088, wih_bf, 1088, b_ih, gi, 3 * HID, BAT, 1088,
        nullptr, 0, nullptr, nullptr);
    gru_combine<<<dim3(1024), blk, 0, stream>>>(gi, hgh + HID, 4 * HID, ldh, out_hid, hid_bf);
    gemm_bf<2><<<dim3(2, 8), blk, 0, stream>>>(
        hid_bf, HID, o1_bf, HID, o1_b, x1, HID, BAT, HID,
        nullptr, 0, nullptr, nullptr);
    bn_stats<<<dim3(4), blk, 0, stream>>>(x1, bnw, bnb, sj, tj);
    palette_kernel<<<dim3(256), blk, 0, stream>>>(x1, sj, tj, o2_w, o2_b, out_pal);
  } else {
    // -------- tier 3: fp32 fallback --------
    char* q = p0;
    auto carve2 = [&](size_t bytes) { char* r = q; q += (bytes + 255) & ~(size_t)255; return r; };
    float* hws2   = (float*)carve2((size_t)BAT * HID * 4);
    float* epart2 = (float*)carve2((size_t)8 * SEQ * BAT * 4);
    float* wsm2   = (float*)carve2((size_t)SEQ * BAT * 4);
    float* gin2   = (float*)carve2((size_t)BAT * 1088 * 4);
    float* gi2    = (float*)carve2((size_t)BAT * 3 * HID * 4);
    float* gh2    = (float*)carve2((size_t)BAT * 3 * HID * 4);
    float* x12    = (float*)carve2((size_t)BAT * HID * 4);
    float* sj2    = (float*)carve2((size_t)HID * 4);
    float* tj2    = (float*)carve2((size_t)HID * 4);

    gemm_bt<0, false><<<dim3(2, 8), blk, 0, stream>>>(
        ldh, HID, h_w, HID, HID, h_b, hws2, HID, BAT, HID, nullptr, nullptr, nullptr);
    gemm_bt<1, false><<<dim3(512, 8), blk, 0, stream>>>(
        enc, HID, e_w, HID, HID, e_b, nullptr, 0, SEQ * BAT, HID, hws2, en_w, epart2);
    gemm_bt<0, false><<<dim3(2, 24), blk, 0, stream>>>(
        ldh, HID, w_hh, HID, HID, b_hh, gh2, 3 * HID, BAT, HID, nullptr, nullptr, nullptr);
    softmax_kernel<<<dim3(256), blk, 0, stream>>>(epart2, 8, wsm2, out_att);
    prep_gin<<<dim3(1), blk, 0, stream>>>(pal_in, gin2);
    context_kernel<<<dim3(256, 4), blk, 0, stream>>>(enc, wsm2, out_ctx, gin2);
    gemm_bt<0, true><<<dim3(2, 24), blk, 0, stream>>>(
        gin2, 1088, w_ih, 1027, 1027, b_ih, gi2, 3 * HID, BAT, 1088, nullptr, nullptr, nullptr);
    gru_combine<<<dim3(1024), blk, 0, stream>>>(gi2, gh2, 3 * HID, ldh, out_hid, nullptr);
    gemm_bt<2, false><<<dim3(2, 8), blk, 0, stream>>>(
        out_hid, HID, o1_w, HID, HID, o1_b, x12, HID, BAT, HID, nullptr, nullptr, nullptr);
    bn_stats<<<dim3(4), blk, 0, stream>>>(x12, bnw, bnb, sj2, tj2);
    palette_kernel<<<dim3(256), blk, 0, stream>>>(x12, sj2, tj2, o2_w, o2_b, out_pal);
  }
}